// Round 10
// baseline (134.113 us; speedup 1.0000x reference)
//
#include <hip/hip_runtime.h>
#include <stdint.h>

#define B 128
#define F 8192
#define H 8192
#define S 4
#define K 32
#define L 3
#define C 100

// ---------------------------------------------------------------------------
// Pack x (B,F) float {0,1} -> PLANAR u32 bit tables xP[w][f], w = b>>5,
// bit = b & 31. Grid 1024 x 128 (8 f per block) for 2 waves/SIMD occupancy.
// Also zeroes d_out (fused, saves a launch).
// ---------------------------------------------------------------------------
__global__ void pack_x_kernel(const float* __restrict__ x, uint32_t* __restrict__ xP,
                              float* __restrict__ out) {
    const int zi = blockIdx.x * 128 + threadIdx.x;
    if (zi < B * C) out[zi] = 0.0f;

    const int b = threadIdx.x;           // 0..127
    const int wv = threadIdx.x >> 6;     // wave id (0,1)
    const int f0 = blockIdx.x * 8;
    const float4* xr = (const float4*)(x + (size_t)b * F + f0);
#pragma unroll
    for (int j = 0; j < 2; ++j) {
        const float4 v = xr[j];
        const uint64_t m0 = __ballot(v.x > 0.5f);
        const uint64_t m1 = __ballot(v.y > 0.5f);
        const uint64_t m2 = __ballot(v.z > 0.5f);
        const uint64_t m3 = __ballot(v.w > 0.5f);
        if ((threadIdx.x & 63) == 0) {
            const int f = f0 + 4 * j;
            uint32_t* lo = xP + (size_t)(2 * wv) * F;
            uint32_t* hi = xP + (size_t)(2 * wv + 1) * F;
            lo[f + 0] = (uint32_t)m0;  hi[f + 0] = (uint32_t)(m0 >> 32);
            lo[f + 1] = (uint32_t)m1;  hi[f + 1] = (uint32_t)(m1 >> 32);
            lo[f + 2] = (uint32_t)m2;  hi[f + 2] = (uint32_t)(m2 >> 32);
            lo[f + 3] = (uint32_t)m3;  hi[f + 3] = (uint32_t)(m3 >> 32);
        }
    }
}

__device__ __forceinline__ int load_threshold(const int* p) {
    // threshold is a tiny int; guard against the harness storing it as f32 bits
    int v = *p;
    if (v >= (1 << 23)) v = (int)__int_as_float(v);
    return v;
}

// ---------------------------------------------------------------------------
// BIT-SLICED u32 layer body (proven R9 code). blockIdx bid = hg*4 + w.
// ---------------------------------------------------------------------------
#define ISG_STRIDE 40

__device__ __forceinline__ void layer_body(const uint32_t* __restrict__ prevP,
                                           const int* __restrict__ idx,
                                           const float* __restrict__ signs,
                                           uint32_t* __restrict__ outP,
                                           const int thr, const int bid,
                                           uint32_t* tab, uint32_t* isg,
                                           uint32_t* fbuf) {
    const int tid  = threadIdx.x;
    const int lane = tid & 63;
    const int sw   = tid >> 6;               // wave = segment
    const int w    = bid & 3;
    const int hg   = bid >> 2;
    const int h    = hg * 64 + lane;

    // ---- stage tab (word-w plane, 32 KiB, coalesced int4) ----
    {
        const int4* src = (const int4*)(prevP + (size_t)w * H);
        int4* dst = (int4*)tab;
#pragma unroll
        for (int i = 0; i < 8; ++i)
            dst[i * 256 + tid] = src[i * 256 + tid];
    }
    // ---- stage idx/sign tiles: per s, 2048 ints contiguous; uint4 stores ----
    {
        const int hrow = tid >> 2;
        const int k0   = (tid & 3) * 8;
#pragma unroll
        for (int s = 0; s < S; ++s) {
            const int4*   ib = (const int4*)(idx   + ((size_t)s * H + hg * 64) * K);
            const float4* sb = (const float4*)(signs + ((size_t)s * H + hg * 64) * K);
            const int4   ia = ib[2 * tid],  ic = ib[2 * tid + 1];
            const float4 sa = sb[2 * tid],  sc = sb[2 * tid + 1];
            uint4* dst = (uint4*)(isg + s * (64 * ISG_STRIDE) + hrow * ISG_STRIDE + k0);
            uint4 p0, p1;
            p0.x = (uint32_t)ia.x | ((uint32_t)__float_as_int(sa.x) & 0x80000000u);
            p0.y = (uint32_t)ia.y | ((uint32_t)__float_as_int(sa.y) & 0x80000000u);
            p0.z = (uint32_t)ia.z | ((uint32_t)__float_as_int(sa.z) & 0x80000000u);
            p0.w = (uint32_t)ia.w | ((uint32_t)__float_as_int(sa.w) & 0x80000000u);
            p1.x = (uint32_t)ic.x | ((uint32_t)__float_as_int(sc.x) & 0x80000000u);
            p1.y = (uint32_t)ic.y | ((uint32_t)__float_as_int(sc.y) & 0x80000000u);
            p1.z = (uint32_t)ic.z | ((uint32_t)__float_as_int(sc.z) & 0x80000000u);
            p1.w = (uint32_t)ic.w | ((uint32_t)__float_as_int(sc.w) & 0x80000000u);
            dst[0] = p0;
            dst[1] = p1;
        }
    }
    __syncthreads();

    // ---- gather + bit-sliced accumulate ----
    uint32_t A[6] = {0, 0, 0, 0, 0, 0};      // sum of a      (<=32)
    uint32_t P[6] = {0, 0, 0, 0, 0, 0};      // sum of a&pos  (<=32)
    const uint4* row4 = (const uint4*)(isg + sw * (64 * ISG_STRIDE) + lane * ISG_STRIDE);
#pragma unroll
    for (int c = 0; c < 4; ++c) {
        const uint4 r0 = row4[2 * c];
        const uint4 r1 = row4[2 * c + 1];
        const uint32_t iv[8] = {r0.x, r0.y, r0.z, r0.w, r1.x, r1.y, r1.z, r1.w};
        uint32_t a[8];
#pragma unroll
        for (int j = 0; j < 8; ++j) a[j] = tab[iv[j] & 0xFFFFu];
#pragma unroll
        for (int j = 0; j < 8; ++j) {
            const uint32_t pm = ~(uint32_t)((int32_t)iv[j] >> 31); // ~0 if pos
            uint32_t cc = a[j];
#pragma unroll
            for (int i = 0; i < 6; ++i) { const uint32_t t = A[i]; A[i] = t ^ cc; cc = t & cc; }
            cc = a[j] & pm;
#pragma unroll
            for (int i = 0; i < 6; ++i) { const uint32_t t = P[i]; P[i] = t ^ cc; cc = t & cc; }
        }
    }

    // ---- fired = (2P >= A + thr), 7-bit bit-sliced compare ----
    uint32_t Y[7];
    {
        uint32_t c = 0;
#pragma unroll
        for (int i = 0; i < 7; ++i) {
            const uint32_t ai = (i < 6) ? A[i] : 0u;
            const uint32_t bm = ((thr >> i) & 1) ? 0xFFFFFFFFu : 0u;
            const uint32_t t  = ai ^ bm;
            Y[i] = t ^ c;
            c = (ai & bm) | (t & c);
        }
    }
    uint32_t bw = 0;
#pragma unroll
    for (int i = 0; i < 7; ++i) {
        const uint32_t xx = (i >= 1) ? P[i - 1] : 0u;
        const uint32_t d  = xx ^ Y[i];
        bw = ((~xx) & Y[i]) | ((~d) & bw);
    }
    const uint32_t fired = ~bw;

    // ---- OR across the 4 segment-waves ----
    fbuf[sw * 64 + lane] = fired;
    __syncthreads();
    if (sw == 0) {
        const uint32_t f = fbuf[lane] | fbuf[64 + lane] |
                           fbuf[128 + lane] | fbuf[192 + lane];
        outP[(size_t)w * H + h] = f;             // coalesced 4B stores
    }
}

__global__ void layer_kernel(const uint32_t* __restrict__ prevP,
                             const int* __restrict__ idx,
                             const float* __restrict__ signs,
                             uint32_t* __restrict__ outP,
                             const int* __restrict__ thrp) {
    __shared__ uint32_t tab[H];                       // 32 KiB
    __shared__ uint32_t isg[S * 64 * ISG_STRIDE];     // 40 KiB
    __shared__ uint32_t fbuf[256];                    // 1 KiB
    layer_body(prevP, idx, signs, outP, load_threshold(thrp), blockIdx.x,
               tab, isg, fbuf);
}

// ---------------------------------------------------------------------------
// Final-einsum body for layers [lbeg, lend]: wave = one b, lanes = c.
// item in [0,1024): hc = item & 31, bg = item >> 5. Walk ~set bits of the
// 64-h mask (ballot), coalesced wout-row loads, <=2 atomics per lane.
// ---------------------------------------------------------------------------
#define NHC 32
#define HCH (H / NHC)   // 256 h per chunk

__device__ __forceinline__ void final_body(const uint32_t* __restrict__ actP,
                                           const float* __restrict__ wout,
                                           float* __restrict__ out,
                                           const int item, const int lbeg,
                                           const int lend) {
    const int lane = threadIdx.x & 63;
    const int wid  = threadIdx.x >> 6;          // 0..3
    const int hc   = item & (NHC - 1);
    const int bg   = item / NHC;                // 0..31
    const int b    = bg * 4 + wid;              // wave-uniform
    const int w32  = b >> 5;                    // uniform within wave
    const int bit  = b & 31;

    float acc0 = 0.0f, acc1 = 0.0f;
    const int c1 = 64 + lane;
    const bool c1v = (c1 < C);

    for (int l = lbeg; l <= lend; ++l) {
        const uint32_t* aT = actP + ((size_t)l * 4 + w32) * H;
        const float* wl = wout + (size_t)l * H * C;
        for (int r = 0; r < HCH / 64; ++r) {
            const int hbase = hc * HCH + r * 64;
            const uint32_t m = aT[hbase + lane];
            uint64_t hm = __ballot((m >> bit) & 1u);
            while (hm) {
                const int slot = __ffsll((unsigned long long)hm) - 1;
                hm &= hm - 1;
                const float* wr = wl + (size_t)(hbase + slot) * C;
                acc0 += wr[lane];
                if (c1v) acc1 += wr[c1];
            }
        }
    }
    atomicAdd(&out[b * C + lane], acc0);
    if (c1v) atomicAdd(&out[b * C + c1], acc1);
}

// ---------------------------------------------------------------------------
// L2 + final01 fused by ROLE: blocks 0..511 compute layer 2 (actP[2]);
// blocks 512..1535 compute the l=0,1 part of the final einsum (needs only
// actP[0..1], already written by earlier kernels -> no dependency on the
// layer-role blocks). Hides final01 entirely under L2's dispatch.
// ---------------------------------------------------------------------------
__global__ void layer2_final01_kernel(const uint32_t* __restrict__ prevP,
                                      const int* __restrict__ idx,
                                      const float* __restrict__ signs,
                                      uint32_t* __restrict__ outP,
                                      const int* __restrict__ thrp,
                                      const uint32_t* __restrict__ actP,
                                      const float* __restrict__ wout,
                                      float* __restrict__ out) {
    __shared__ uint32_t tab[H];                       // 32 KiB
    __shared__ uint32_t isg[S * 64 * ISG_STRIDE];     // 40 KiB
    __shared__ uint32_t fbuf[256];                    // 1 KiB
    if (blockIdx.x < 512) {
        layer_body(prevP, idx, signs, outP, load_threshold(thrp), blockIdx.x,
                   tab, isg, fbuf);
    } else {
        final_body(actP, wout, out, blockIdx.x - 512, 0, 1);
    }
}

// Trailing kernel: only the l=2 plane (near-empty -> ~mask-scan only).
__global__ void final2_kernel(const uint32_t* __restrict__ actP,
                              const float* __restrict__ wout,
                              float* __restrict__ out) {
    final_body(actP, wout, out, blockIdx.x, 2, 2);
}

// ---------------------------------------------------------------------------
extern "C" void kernel_launch(void* const* d_in, const int* in_sizes, int n_in,
                              void* d_out, int out_size, void* d_ws, size_t ws_size,
                              hipStream_t stream) {
    const float* x      = (const float*)d_in[0];   // (B,F)
    const float* signs0 = (const float*)d_in[1];   // (S,H,K)
    const float* signsH = (const float*)d_in[2];   // (L-1,S,H,K)
    const float* wout   = (const float*)d_in[3];   // (L,H,C)
    const int*   idx0   = (const int*)d_in[4];     // (S,H,K)
    const int*   idxH   = (const int*)d_in[5];     // (L-1,S,H,K)
    const int*   thr    = (const int*)d_in[6];     // scalar
    float* out = (float*)d_out;                    // (B,C)

    // Workspace (planar u32): xP [4][F] (128 KiB), actP [L][4][H] (384 KiB)
    uint32_t* xP   = (uint32_t*)d_ws;
    uint32_t* actP = xP + (size_t)4 * F;

    // pack x + zero out (fused); 1024 blocks for occupancy
    pack_x_kernel<<<1024, 128, 0, stream>>>(x, xP, out);

    // layers 0,1: grid = 128 h-groups x 4 words = 512 blocks
    layer_kernel<<<512, 256, 0, stream>>>(xP, idx0, signs0, actP, thr);
    layer_kernel<<<512, 256, 0, stream>>>(actP, idxH, signsH,
                                          actP + (size_t)4 * H, thr);
    // layer 2 + final(l=0,1) fused by role
    layer2_final01_kernel<<<1536, 256, 0, stream>>>(
        actP + (size_t)4 * H,
        idxH + (size_t)S * H * K,
        signsH + (size_t)S * H * K,
        actP + (size_t)8 * H, thr,
        actP, wout, out);
    // final(l=2) only
    final2_kernel<<<1024, 256, 0, stream>>>(actP, wout, out);
}

// Round 11
// 130.094 us; speedup vs baseline: 1.0309x; 1.0309x over previous
//
#include <hip/hip_runtime.h>
#include <stdint.h>

#define B 128
#define F 8192
#define H 8192
#define S 4
#define K 32
#define L 3
#define C 100

// ---------------------------------------------------------------------------
// Pack x (B,F) float {0,1} -> PLANAR u32 bit tables xP[w][f], w = b>>5,
// bit = b & 31. Block = 128 threads (thread = b), 32 f per block.
// Also zeroes d_out (fused, saves a launch).  [R9-proven]
// ---------------------------------------------------------------------------
__global__ void pack_x_kernel(const float* __restrict__ x, uint32_t* __restrict__ xP,
                              float* __restrict__ out) {
    const int zi = blockIdx.x * 128 + threadIdx.x;
    if (zi < B * C) out[zi] = 0.0f;

    const int b = threadIdx.x;           // 0..127
    const int wv = threadIdx.x >> 6;     // wave id (0,1)
    const int f0 = blockIdx.x * 32;
    const float4* xr = (const float4*)(x + (size_t)b * F + f0);
    for (int j = 0; j < 8; ++j) {
        const float4 v = xr[j];
        const uint64_t m0 = __ballot(v.x > 0.5f);
        const uint64_t m1 = __ballot(v.y > 0.5f);
        const uint64_t m2 = __ballot(v.z > 0.5f);
        const uint64_t m3 = __ballot(v.w > 0.5f);
        if ((threadIdx.x & 63) == 0) {
            const int f = f0 + 4 * j;
            uint32_t* lo = xP + (size_t)(2 * wv) * F;
            uint32_t* hi = xP + (size_t)(2 * wv + 1) * F;
            lo[f + 0] = (uint32_t)m0;  hi[f + 0] = (uint32_t)(m0 >> 32);
            lo[f + 1] = (uint32_t)m1;  hi[f + 1] = (uint32_t)(m1 >> 32);
            lo[f + 2] = (uint32_t)m2;  hi[f + 2] = (uint32_t)(m2 >> 32);
            lo[f + 3] = (uint32_t)m3;  hi[f + 3] = (uint32_t)(m3 >> 32);
        }
    }
}

__device__ __forceinline__ int load_threshold(const int* p) {
    // threshold is a tiny int; guard against the harness storing it as f32 bits
    int v = *p;
    if (v >= (1 << 23)) v = (int)__int_as_float(v);
    return v;
}

// ---------------------------------------------------------------------------
// BIT-SLICED u32 layer: prevP[w][hprev] (planar u32, w=0..3) -> outP[w][h].
// lane = neuron h (64 h per wave); the 32-batch mask word is per-lane DATA.
// Block = 256 = 4 waves; wave = segment s. blockIdx = hg*4 + w.
// R11 change vs R9: NO isg LDS staging — each lane's 32 idx + 32 signs are
// its own contiguous 256 B, read directly (uint4/float4, L3-warm) and merged
// in registers. LDS = tab 32 KiB + fbuf 1 KiB -> 4 blocks/CU (16 waves/CU),
// one fewer barrier, no LDS round-trip for isg.
// ---------------------------------------------------------------------------
__global__ void layer_kernel(const uint32_t* __restrict__ prevP,
                             const int* __restrict__ idx,
                             const float* __restrict__ signs,
                             uint32_t* __restrict__ outP,
                             const int* __restrict__ thrp) {
    __shared__ uint32_t tab[H];              // 32 KiB
    __shared__ uint32_t fbuf[256];           // 1 KiB
    const int tid  = threadIdx.x;
    const int lane = tid & 63;
    const int sw   = tid >> 6;               // wave = segment
    const int w    = blockIdx.x & 3;
    const int hg   = blockIdx.x >> 2;
    const int h    = hg * 64 + lane;
    const int thr  = load_threshold(thrp);

    // ---- stage tab (word-w plane, 32 KiB, coalesced int4) ----
    {
        const int4* src = (const int4*)(prevP + (size_t)w * H);
        int4* dst = (int4*)tab;
#pragma unroll
        for (int i = 0; i < 8; ++i)
            dst[i * 256 + tid] = src[i * 256 + tid];
    }
    __syncthreads();

    // ---- per-lane direct reads of idx/signs + gather + bit-sliced accumulate
    uint32_t A[6] = {0, 0, 0, 0, 0, 0};      // sum of a      (<=32)
    uint32_t P[6] = {0, 0, 0, 0, 0, 0};      // sum of a&pos  (<=32)
    const uint4*  ip = (const uint4*)(idx   + ((size_t)sw * H + h) * K);
    const float4* sp = (const float4*)(signs + ((size_t)sw * H + h) * K);
#pragma unroll
    for (int c = 0; c < 4; ++c) {
        const uint4  i0 = ip[2 * c],  i1 = ip[2 * c + 1];
        const float4 s0 = sp[2 * c],  s1 = sp[2 * c + 1];
        uint32_t iv[8];
        iv[0] = i0.x | ((uint32_t)__float_as_int(s0.x) & 0x80000000u);
        iv[1] = i0.y | ((uint32_t)__float_as_int(s0.y) & 0x80000000u);
        iv[2] = i0.z | ((uint32_t)__float_as_int(s0.z) & 0x80000000u);
        iv[3] = i0.w | ((uint32_t)__float_as_int(s0.w) & 0x80000000u);
        iv[4] = i1.x | ((uint32_t)__float_as_int(s1.x) & 0x80000000u);
        iv[5] = i1.y | ((uint32_t)__float_as_int(s1.y) & 0x80000000u);
        iv[6] = i1.z | ((uint32_t)__float_as_int(s1.z) & 0x80000000u);
        iv[7] = i1.w | ((uint32_t)__float_as_int(s1.w) & 0x80000000u);
        uint32_t a[8];
#pragma unroll
        for (int j = 0; j < 8; ++j) a[j] = tab[iv[j] & 0xFFFFu];  // ~2/bank, free
#pragma unroll
        for (int j = 0; j < 8; ++j) {
            const uint32_t pm = ~(uint32_t)((int32_t)iv[j] >> 31); // ~0 if pos
            uint32_t cc = a[j];
#pragma unroll
            for (int i = 0; i < 6; ++i) { const uint32_t t = A[i]; A[i] = t ^ cc; cc = t & cc; }
            cc = a[j] & pm;
#pragma unroll
            for (int i = 0; i < 6; ++i) { const uint32_t t = P[i]; P[i] = t ^ cc; cc = t & cc; }
        }
    }

    // ---- fired = (2P >= A + thr), 7-bit bit-sliced compare ----
    uint32_t Y[7];
    {
        uint32_t c = 0;
#pragma unroll
        for (int i = 0; i < 7; ++i) {
            const uint32_t ai = (i < 6) ? A[i] : 0u;
            const uint32_t bm = ((thr >> i) & 1) ? 0xFFFFFFFFu : 0u;
            const uint32_t t  = ai ^ bm;
            Y[i] = t ^ c;
            c = (ai & bm) | (t & c);
        }
    }
    uint32_t bw = 0;
#pragma unroll
    for (int i = 0; i < 7; ++i) {
        const uint32_t xx = (i >= 1) ? P[i - 1] : 0u;
        const uint32_t d  = xx ^ Y[i];
        bw = ((~xx) & Y[i]) | ((~d) & bw);
    }
    const uint32_t fired = ~bw;

    // ---- OR across the 4 segment-waves ----
    fbuf[sw * 64 + lane] = fired;
    __syncthreads();
    if (sw == 0) {
        const uint32_t f = fbuf[lane] | fbuf[64 + lane] |
                           fbuf[128 + lane] | fbuf[192 + lane];
        outP[(size_t)w * H + h] = f;             // coalesced 4B stores
    }
}

// ---------------------------------------------------------------------------
// out[b][c] = sum_l sum_h act[l][b][h] * wout[l][h][c], act in {0,1}.
// Wave = one b; lanes = c (acc in 2 VGPRs: c=lane, c=lane+64).
// Grid = 32 b-groups x NHC h-chunks; block = 256 (4 waves = 4 consecutive b).
// NHC=32 -> 1024 blocks = 4 blocks/CU = 16 waves/CU.  [R9-proven]
// Planar u32 masks: actP[(l*4 + (b>>5))*H + h], bit = b & 31.
// ---------------------------------------------------------------------------
#define NHC 32
#define HCH (H / NHC)   // 256 h per chunk

__global__ void final_kernel(const uint32_t* __restrict__ actP,
                             const float* __restrict__ wout,
                             float* __restrict__ out) {
    const int lane = threadIdx.x & 63;
    const int wid  = threadIdx.x >> 6;          // 0..3
    const int hc   = blockIdx.x & (NHC - 1);
    const int bg   = blockIdx.x / NHC;          // 0..31
    const int b    = bg * 4 + wid;              // wave-uniform
    const int w32  = b >> 5;                    // uniform within wave
    const int bit  = b & 31;

    float acc0 = 0.0f, acc1 = 0.0f;
    const int c1 = 64 + lane;
    const bool c1v = (c1 < C);

    for (int l = 0; l < L; ++l) {
        const uint32_t* aT = actP + ((size_t)l * 4 + w32) * H;
        const float* wl = wout + (size_t)l * H * C;
        for (int r = 0; r < HCH / 64; ++r) {
            const int hbase = hc * HCH + r * 64;
            const uint32_t m = aT[hbase + lane];
            uint64_t hm = __ballot((m >> bit) & 1u);
            while (hm) {
                const int slot = __ffsll((unsigned long long)hm) - 1;
                hm &= hm - 1;
                const float* wr = wl + (size_t)(hbase + slot) * C;
                acc0 += wr[lane];
                if (c1v) acc1 += wr[c1];
            }
        }
    }
    atomicAdd(&out[b * C + lane], acc0);
    if (c1v) atomicAdd(&out[b * C + c1], acc1);
}

// ---------------------------------------------------------------------------
extern "C" void kernel_launch(void* const* d_in, const int* in_sizes, int n_in,
                              void* d_out, int out_size, void* d_ws, size_t ws_size,
                              hipStream_t stream) {
    const float* x      = (const float*)d_in[0];   // (B,F)
    const float* signs0 = (const float*)d_in[1];   // (S,H,K)
    const float* signsH = (const float*)d_in[2];   // (L-1,S,H,K)
    const float* wout   = (const float*)d_in[3];   // (L,H,C)
    const int*   idx0   = (const int*)d_in[4];     // (S,H,K)
    const int*   idxH   = (const int*)d_in[5];     // (L-1,S,H,K)
    const int*   thr    = (const int*)d_in[6];     // scalar
    float* out = (float*)d_out;                    // (B,C)

    // Workspace (planar u32): xP [4][F] (128 KiB), actP [L][4][H] (384 KiB)
    uint32_t* xP   = (uint32_t*)d_ws;
    uint32_t* actP = xP + (size_t)4 * F;

    // pack x + zero out (fused)
    pack_x_kernel<<<F / 32, 128, 0, stream>>>(x, xP, out);

    // layers: grid = 128 h-groups x 4 words = 512 blocks, 4 segment-waves each
    layer_kernel<<<512, 256, 0, stream>>>(xP, idx0, signs0, actP, thr);
    layer_kernel<<<512, 256, 0, stream>>>(actP, idxH, signsH,
                                          actP + (size_t)4 * H, thr);
    layer_kernel<<<512, 256, 0, stream>>>(actP + (size_t)4 * H,
                                          idxH + (size_t)S * H * K,
                                          signsH + (size_t)S * H * K,
                                          actP + (size_t)8 * H, thr);

    final_kernel<<<32 * NHC, 256, 0, stream>>>(actP, wout, out);
}

// Round 12
// 126.699 us; speedup vs baseline: 1.0585x; 1.0268x over previous
//
#include <hip/hip_runtime.h>
#include <stdint.h>

#define B 128
#define F 8192
#define H 8192
#define S 4
#define K 32
#define L 3
#define C 100

// ---------------------------------------------------------------------------
// Pack x (B,F) float {0,1} -> PLANAR u32 bit tables xP[w][f], w = b>>5,
// bit = b & 31. Block = 128 threads (thread = b), 32 f per block.
// Also zeroes d_out (fused, saves a launch).  [R9-proven]
// ---------------------------------------------------------------------------
__global__ void pack_x_kernel(const float* __restrict__ x, uint32_t* __restrict__ xP,
                              float* __restrict__ out) {
    const int zi = blockIdx.x * 128 + threadIdx.x;
    if (zi < B * C) out[zi] = 0.0f;

    const int b = threadIdx.x;           // 0..127
    const int wv = threadIdx.x >> 6;     // wave id (0,1)
    const int f0 = blockIdx.x * 32;
    const float4* xr = (const float4*)(x + (size_t)b * F + f0);
    for (int j = 0; j < 8; ++j) {
        const float4 v = xr[j];
        const uint64_t m0 = __ballot(v.x > 0.5f);
        const uint64_t m1 = __ballot(v.y > 0.5f);
        const uint64_t m2 = __ballot(v.z > 0.5f);
        const uint64_t m3 = __ballot(v.w > 0.5f);
        if ((threadIdx.x & 63) == 0) {
            const int f = f0 + 4 * j;
            uint32_t* lo = xP + (size_t)(2 * wv) * F;
            uint32_t* hi = xP + (size_t)(2 * wv + 1) * F;
            lo[f + 0] = (uint32_t)m0;  hi[f + 0] = (uint32_t)(m0 >> 32);
            lo[f + 1] = (uint32_t)m1;  hi[f + 1] = (uint32_t)(m1 >> 32);
            lo[f + 2] = (uint32_t)m2;  hi[f + 2] = (uint32_t)(m2 >> 32);
            lo[f + 3] = (uint32_t)m3;  hi[f + 3] = (uint32_t)(m3 >> 32);
        }
    }
}

__device__ __forceinline__ int load_threshold(const int* p) {
    // threshold is a tiny int; guard against the harness storing it as f32 bits
    int v = *p;
    if (v >= (1 << 23)) v = (int)__int_as_float(v);
    return v;
}

// ---------------------------------------------------------------------------
// BIT-SLICED u32 layer body [R9-proven, verbatim]. bid = hg*4 + w.
// Returns the OR'd fired word (valid in wave sw==0; 0 elsewhere).
// ---------------------------------------------------------------------------
#define ISG_STRIDE 40

__device__ __forceinline__ uint32_t layer_body(const uint32_t* __restrict__ prevP,
                                               const int* __restrict__ idx,
                                               const float* __restrict__ signs,
                                               uint32_t* __restrict__ outP,
                                               const int thr, const int bid,
                                               uint32_t* tab, uint32_t* isg,
                                               uint32_t* fbuf) {
    const int tid  = threadIdx.x;
    const int lane = tid & 63;
    const int sw   = tid >> 6;               // wave = segment
    const int w    = bid & 3;
    const int hg   = bid >> 2;
    const int h    = hg * 64 + lane;

    // ---- stage tab (word-w plane, 32 KiB, coalesced int4) ----
    {
        const int4* src = (const int4*)(prevP + (size_t)w * H);
        int4* dst = (int4*)tab;
#pragma unroll
        for (int i = 0; i < 8; ++i)
            dst[i * 256 + tid] = src[i * 256 + tid];
    }
    // ---- stage idx/sign tiles: per s, 2048 ints contiguous; uint4 stores ----
    {
        const int hrow = tid >> 2;
        const int k0   = (tid & 3) * 8;
#pragma unroll
        for (int s = 0; s < S; ++s) {
            const int4*   ib = (const int4*)(idx   + ((size_t)s * H + hg * 64) * K);
            const float4* sb = (const float4*)(signs + ((size_t)s * H + hg * 64) * K);
            const int4   ia = ib[2 * tid],  ic = ib[2 * tid + 1];
            const float4 sa = sb[2 * tid],  sc = sb[2 * tid + 1];
            uint4* dst = (uint4*)(isg + s * (64 * ISG_STRIDE) + hrow * ISG_STRIDE + k0);
            uint4 p0, p1;
            p0.x = (uint32_t)ia.x | ((uint32_t)__float_as_int(sa.x) & 0x80000000u);
            p0.y = (uint32_t)ia.y | ((uint32_t)__float_as_int(sa.y) & 0x80000000u);
            p0.z = (uint32_t)ia.z | ((uint32_t)__float_as_int(sa.z) & 0x80000000u);
            p0.w = (uint32_t)ia.w | ((uint32_t)__float_as_int(sa.w) & 0x80000000u);
            p1.x = (uint32_t)ic.x | ((uint32_t)__float_as_int(sc.x) & 0x80000000u);
            p1.y = (uint32_t)ic.y | ((uint32_t)__float_as_int(sc.y) & 0x80000000u);
            p1.z = (uint32_t)ic.z | ((uint32_t)__float_as_int(sc.z) & 0x80000000u);
            p1.w = (uint32_t)ic.w | ((uint32_t)__float_as_int(sc.w) & 0x80000000u);
            dst[0] = p0;
            dst[1] = p1;
        }
    }
    __syncthreads();

    // ---- gather + bit-sliced accumulate ----
    uint32_t A[6] = {0, 0, 0, 0, 0, 0};      // sum of a      (<=32)
    uint32_t P[6] = {0, 0, 0, 0, 0, 0};      // sum of a&pos  (<=32)
    const uint4* row4 = (const uint4*)(isg + sw * (64 * ISG_STRIDE) + lane * ISG_STRIDE);
#pragma unroll
    for (int c = 0; c < 4; ++c) {
        const uint4 r0 = row4[2 * c];
        const uint4 r1 = row4[2 * c + 1];
        const uint32_t iv[8] = {r0.x, r0.y, r0.z, r0.w, r1.x, r1.y, r1.z, r1.w};
        uint32_t a[8];
#pragma unroll
        for (int j = 0; j < 8; ++j) a[j] = tab[iv[j] & 0xFFFFu];
#pragma unroll
        for (int j = 0; j < 8; ++j) {
            const uint32_t pm = ~(uint32_t)((int32_t)iv[j] >> 31); // ~0 if pos
            uint32_t cc = a[j];
#pragma unroll
            for (int i = 0; i < 6; ++i) { const uint32_t t = A[i]; A[i] = t ^ cc; cc = t & cc; }
            cc = a[j] & pm;
#pragma unroll
            for (int i = 0; i < 6; ++i) { const uint32_t t = P[i]; P[i] = t ^ cc; cc = t & cc; }
        }
    }

    // ---- fired = (2P >= A + thr), 7-bit bit-sliced compare ----
    uint32_t Y[7];
    {
        uint32_t c = 0;
#pragma unroll
        for (int i = 0; i < 7; ++i) {
            const uint32_t ai = (i < 6) ? A[i] : 0u;
            const uint32_t bm = ((thr >> i) & 1) ? 0xFFFFFFFFu : 0u;
            const uint32_t t  = ai ^ bm;
            Y[i] = t ^ c;
            c = (ai & bm) | (t & c);
        }
    }
    uint32_t bw = 0;
#pragma unroll
    for (int i = 0; i < 7; ++i) {
        const uint32_t xx = (i >= 1) ? P[i - 1] : 0u;
        const uint32_t d  = xx ^ Y[i];
        bw = ((~xx) & Y[i]) | ((~d) & bw);
    }
    const uint32_t fired = ~bw;

    // ---- OR across the 4 segment-waves ----
    fbuf[sw * 64 + lane] = fired;
    __syncthreads();
    uint32_t f = 0;
    if (sw == 0) {
        f = fbuf[lane] | fbuf[64 + lane] |
            fbuf[128 + lane] | fbuf[192 + lane];
        outP[(size_t)w * H + h] = f;             // coalesced 4B stores
    }
    return f;
}

__global__ void layer_kernel(const uint32_t* __restrict__ prevP,
                             const int* __restrict__ idx,
                             const float* __restrict__ signs,
                             uint32_t* __restrict__ outP,
                             const int* __restrict__ thrp) {
    __shared__ uint32_t tab[H];                       // 32 KiB
    __shared__ uint32_t isg[S * 64 * ISG_STRIDE];     // 40 KiB
    __shared__ uint32_t fbuf[256];                    // 1 KiB
    layer_body(prevP, idx, signs, outP, load_threshold(thrp), blockIdx.x,
               tab, isg, fbuf);
}

// ---------------------------------------------------------------------------
// Final-einsum body for ONE layer l: wave = one b, lanes = c.
// 512 items: hc = item & 15, bg = item >> 4. HCH = 512. 2-deep batched
// set-bit walk keeps 2 independent wout-row loads in flight.
// ---------------------------------------------------------------------------
#define FNHC 16
#define FHCH (H / FNHC)   // 512

__device__ __forceinline__ void final_body(const uint32_t* __restrict__ actP,
                                           const float* __restrict__ wout,
                                           float* __restrict__ out,
                                           const int item, const int l) {
    const int lane = threadIdx.x & 63;
    const int wid  = threadIdx.x >> 6;          // 0..3
    const int hc   = item & (FNHC - 1);
    const int bg   = item / FNHC;               // 0..31
    const int b    = bg * 4 + wid;              // wave-uniform
    const int w32  = b >> 5;                    // uniform within wave
    const int bit  = b & 31;

    float acc0 = 0.0f, acc1 = 0.0f;
    const int c1 = 64 + lane;
    const bool c1v = (c1 < C);

    const uint32_t* aT = actP + ((size_t)l * 4 + w32) * H;
    const float* wl = wout + (size_t)l * H * C;
    for (int r = 0; r < FHCH / 64; ++r) {
        const int hbase = hc * FHCH + r * 64;
        const uint32_t m = aT[hbase + lane];
        uint64_t hm = __ballot((m >> bit) & 1u);
        while (hm) {
            const int s0 = __ffsll((unsigned long long)hm) - 1;
            hm &= hm - 1;
            const float* wr0 = wl + (size_t)(hbase + s0) * C;
            if (hm) {
                const int s1 = __ffsll((unsigned long long)hm) - 1;
                hm &= hm - 1;
                const float* wr1 = wl + (size_t)(hbase + s1) * C;
                const float a0 = wr0[lane];
                const float a1 = wr1[lane];
                const float b0 = c1v ? wr0[c1] : 0.0f;
                const float b1 = c1v ? wr1[c1] : 0.0f;
                acc0 += a0 + a1;
                acc1 += b0 + b1;
            } else {
                acc0 += wr0[lane];
                if (c1v) acc1 += wr0[c1];
            }
        }
    }
    atomicAdd(&out[b * C + lane], acc0);
    if (c1v) atomicAdd(&out[b * C + c1], acc1);
}

// ---------------------------------------------------------------------------
// L1 + final(l=0): layer body then the proven final walk on actP[0]
// (written by the L0 dispatch -> no intra-kernel dependency).
// ---------------------------------------------------------------------------
__global__ void layer1f_kernel(const uint32_t* __restrict__ prevP,
                               const int* __restrict__ idx,
                               const float* __restrict__ signs,
                               uint32_t* __restrict__ outP,
                               const int* __restrict__ thrp,
                               const uint32_t* __restrict__ actP,
                               const float* __restrict__ wout,
                               float* __restrict__ out) {
    __shared__ uint32_t tab[H];
    __shared__ uint32_t isg[S * 64 * ISG_STRIDE];
    __shared__ uint32_t fbuf[256];
    layer_body(prevP, idx, signs, outP, load_threshold(thrp), blockIdx.x,
               tab, isg, fbuf);
    final_body(actP, wout, out, blockIdx.x, 0);
}

// ---------------------------------------------------------------------------
// L2 + final(l=1) + OWN-SLICE final(l=2): the block's wave 0 already holds
// its (hg, w) fired word for layer 2 -> add its l=2 contribution directly
// (density ~0 -> mostly 32 empty ballots). No trailing kernel needed.
// ---------------------------------------------------------------------------
__global__ void layer2f_kernel(const uint32_t* __restrict__ prevP,
                               const int* __restrict__ idx,
                               const float* __restrict__ signs,
                               uint32_t* __restrict__ outP,
                               const int* __restrict__ thrp,
                               const uint32_t* __restrict__ actP,
                               const float* __restrict__ wout,
                               float* __restrict__ out) {
    __shared__ uint32_t tab[H];
    __shared__ uint32_t isg[S * 64 * ISG_STRIDE];
    __shared__ uint32_t fbuf[256];
    const uint32_t f = layer_body(prevP, idx, signs, outP, load_threshold(thrp),
                                  blockIdx.x, tab, isg, fbuf);
    final_body(actP, wout, out, blockIdx.x, 1);

    // own-slice l=2 epilogue (wave 0 only; f is its OR'd fired word)
    if ((threadIdx.x >> 6) == 0) {
        const int lane = threadIdx.x & 63;
        const int w    = blockIdx.x & 3;
        const int hg   = blockIdx.x >> 2;
        const float* w2 = wout + (size_t)2 * H * C;
        const int c1 = 64 + lane;
        const bool c1v = (c1 < C);
#pragma unroll 1
        for (int b = 0; b < 32; ++b) {
            uint64_t hm = __ballot((f >> b) & 1u);
            if (hm == 0ull) continue;
            const int bb = w * 32 + b;
            while (hm) {
                const int slot = __ffsll((unsigned long long)hm) - 1;
                hm &= hm - 1;
                const float* wr = w2 + (size_t)(hg * 64 + slot) * C;
                atomicAdd(&out[bb * C + lane], wr[lane]);
                if (c1v) atomicAdd(&out[bb * C + c1], wr[c1]);
            }
        }
    }
}

// ---------------------------------------------------------------------------
extern "C" void kernel_launch(void* const* d_in, const int* in_sizes, int n_in,
                              void* d_out, int out_size, void* d_ws, size_t ws_size,
                              hipStream_t stream) {
    const float* x      = (const float*)d_in[0];   // (B,F)
    const float* signs0 = (const float*)d_in[1];   // (S,H,K)
    const float* signsH = (const float*)d_in[2];   // (L-1,S,H,K)
    const float* wout   = (const float*)d_in[3];   // (L,H,C)
    const int*   idx0   = (const int*)d_in[4];     // (S,H,K)
    const int*   idxH   = (const int*)d_in[5];     // (L-1,S,H,K)
    const int*   thr    = (const int*)d_in[6];     // scalar
    float* out = (float*)d_out;                    // (B,C)

    // Workspace (planar u32): xP [4][F] (128 KiB), actP [L][4][H] (384 KiB)
    uint32_t* xP   = (uint32_t*)d_ws;
    uint32_t* actP = xP + (size_t)4 * F;

    // 1) pack x + zero out
    pack_x_kernel<<<F / 32, 128, 0, stream>>>(x, xP, out);

    // 2) layer 0
    layer_kernel<<<512, 256, 0, stream>>>(xP, idx0, signs0, actP, thr);

    // 3) layer 1 + final(l=0)
    layer1f_kernel<<<512, 256, 0, stream>>>(actP, idxH, signsH,
                                            actP + (size_t)4 * H, thr,
                                            actP, wout, out);

    // 4) layer 2 + final(l=1) + own-slice final(l=2)
    layer2f_kernel<<<512, 256, 0, stream>>>(actP + (size_t)4 * H,
                                            idxH + (size_t)S * H * K,
                                            signsH + (size_t)S * H * K,
                                            actP + (size_t)8 * H, thr,
                                            actP, wout, out);
}

// Round 13
// 123.294 us; speedup vs baseline: 1.0877x; 1.0276x over previous
//
#include <hip/hip_runtime.h>
#include <stdint.h>

#define B 128
#define F 8192
#define H 8192
#define S 4
#define K 32
#define L 3
#define C 100

// ---------------------------------------------------------------------------
// Pack x (B,F) float {0,1} -> PLANAR u32 bit tables xP[w][f], w = b>>5,
// bit = b & 31. 1024 blocks x 128 threads (8 f per block) for latency hiding.
// Also zeroes d_out (fused, saves a launch).
// ---------------------------------------------------------------------------
__global__ void pack_x_kernel(const float* __restrict__ x, uint32_t* __restrict__ xP,
                              float* __restrict__ out) {
    const int zi = blockIdx.x * 128 + threadIdx.x;
    if (zi < B * C) out[zi] = 0.0f;

    const int b = threadIdx.x;           // 0..127
    const int wv = threadIdx.x >> 6;     // wave id (0,1)
    const int f0 = blockIdx.x * 8;
    const float4* xr = (const float4*)(x + (size_t)b * F + f0);
#pragma unroll
    for (int j = 0; j < 2; ++j) {
        const float4 v = xr[j];
        const uint64_t m0 = __ballot(v.x > 0.5f);
        const uint64_t m1 = __ballot(v.y > 0.5f);
        const uint64_t m2 = __ballot(v.z > 0.5f);
        const uint64_t m3 = __ballot(v.w > 0.5f);
        if ((threadIdx.x & 63) == 0) {
            const int f = f0 + 4 * j;
            uint32_t* lo = xP + (size_t)(2 * wv) * F;
            uint32_t* hi = xP + (size_t)(2 * wv + 1) * F;
            lo[f + 0] = (uint32_t)m0;  hi[f + 0] = (uint32_t)(m0 >> 32);
            lo[f + 1] = (uint32_t)m1;  hi[f + 1] = (uint32_t)(m1 >> 32);
            lo[f + 2] = (uint32_t)m2;  hi[f + 2] = (uint32_t)(m2 >> 32);
            lo[f + 3] = (uint32_t)m3;  hi[f + 3] = (uint32_t)(m3 >> 32);
        }
    }
}

__device__ __forceinline__ int load_threshold(const int* p) {
    // threshold is a tiny int; guard against the harness storing it as f32 bits
    int v = *p;
    if (v >= (1 << 23)) v = (int)__int_as_float(v);
    return v;
}

__device__ __forceinline__ uint32_t pack2(int i0, float s0, int i1, float s1) {
    const uint32_t a = (uint32_t)i0 | (((uint32_t)__float_as_int(s0) & 0x80000000u) >> 16);
    const uint32_t b = (uint32_t)i1 | (((uint32_t)__float_as_int(s1) & 0x80000000u) >> 16);
    return a | (b << 16);
}

// ---------------------------------------------------------------------------
// BIT-SLICED u32 layer: prevP[w][hprev] -> outP[w][h].  [R9 structure]
// Block = 256 = 4 waves; wave = segment s; lane = h. blockIdx = hg*4 + w.
// R13: (1) tab staged via async global_load_lds (width 16, no VGPR
// round-trip, overlaps isg packing); (2) isg packed to u16 = ik | neg<<15
// (13-bit idx), rows of 32 u16 + 8 pad (80 B), one uint4 store / thread /
// segment, 4 ds_read_b128 / lane. LDS 53 KiB.
// ---------------------------------------------------------------------------
#define ISG_ST 40   // u16 units per row (32 + 8 pad) = 80 B

__global__ void layer_kernel(const uint32_t* __restrict__ prevP,
                             const int* __restrict__ idx,
                             const float* __restrict__ signs,
                             uint32_t* __restrict__ outP,
                             const int* __restrict__ thrp) {
    __shared__ uint32_t tab[H];                 // 32 KiB
    __shared__ uint16_t isg[S * 64 * ISG_ST];   // 20 KiB
    __shared__ uint32_t fbuf[256];              // 1 KiB
    const int tid  = threadIdx.x;
    const int lane = tid & 63;
    const int sw   = tid >> 6;                  // wave = segment
    const int w    = blockIdx.x & 3;
    const int hg   = blockIdx.x >> 2;
    const int h    = hg * 64 + lane;
    const int thr  = load_threshold(thrp);

    // ---- tab staging: async DMA, 4 waves x 8 iters x 1 KB ----
    {
        const uint32_t* src = prevP + (size_t)w * H;
#pragma unroll
        for (int i = 0; i < 8; ++i) {
            const int off = (sw * 8 + i) * 256;          // u32 units
            __builtin_amdgcn_global_load_lds(
                (const __attribute__((address_space(1))) uint32_t*)(src + off + lane * 4),
                (__attribute__((address_space(3))) uint32_t*)(tab + off),
                16, 0, 0);
        }
    }
    // ---- isg staging (overlaps the DMA): 8 elems -> one uint4 / thread ----
    {
        const int hrow = tid >> 2;
        const int k0   = (tid & 3) * 8;                  // u16 index in row
#pragma unroll
        for (int s = 0; s < S; ++s) {
            const int4*   ib = (const int4*)(idx   + ((size_t)s * H + hg * 64) * K);
            const float4* sb = (const float4*)(signs + ((size_t)s * H + hg * 64) * K);
            const int4   ia = ib[2 * tid],  ic = ib[2 * tid + 1];
            const float4 sa = sb[2 * tid],  sc = sb[2 * tid + 1];
            uint4 pv;
            pv.x = pack2(ia.x, sa.x, ia.y, sa.y);
            pv.y = pack2(ia.z, sa.z, ia.w, sa.w);
            pv.z = pack2(ic.x, sc.x, ic.y, sc.y);
            pv.w = pack2(ic.z, sc.z, ic.w, sc.w);
            *(uint4*)(&isg[s * (64 * ISG_ST) + hrow * ISG_ST + k0]) = pv;
        }
    }
    __syncthreads();   // drains DMA (vmcnt) + LDS stores (lgkmcnt)

    // ---- gather + bit-sliced accumulate ----
    uint32_t A[6] = {0, 0, 0, 0, 0, 0};      // sum of a      (<=32)
    uint32_t P[6] = {0, 0, 0, 0, 0, 0};      // sum of a&pos  (<=32)
    const uint4* row4 = (const uint4*)(&isg[sw * (64 * ISG_ST) + lane * ISG_ST]);
#pragma unroll
    for (int r = 0; r < 4; ++r) {
        const uint4 q = row4[r];                         // 8 u16 elems
        const uint32_t vv[4] = {q.x, q.y, q.z, q.w};
        uint32_t ik[8], nm[8];
#pragma unroll
        for (int j = 0; j < 4; ++j) {
            ik[2 * j]     = vv[j] & 0x1FFFu;
            nm[2 * j]     = (uint32_t)((int32_t)(vv[j] << 16) >> 31);  // ~0 if neg
            ik[2 * j + 1] = (vv[j] >> 16) & 0x1FFFu;
            nm[2 * j + 1] = (uint32_t)((int32_t)vv[j] >> 31);
        }
        uint32_t a[8];
#pragma unroll
        for (int j = 0; j < 8; ++j) a[j] = tab[ik[j]];
#pragma unroll
        for (int j = 0; j < 8; ++j) {
            const uint32_t pm = ~nm[j];                   // ~0 if positive
            uint32_t cc = a[j];
#pragma unroll
            for (int i = 0; i < 6; ++i) { const uint32_t t = A[i]; A[i] = t ^ cc; cc = t & cc; }
            cc = a[j] & pm;
#pragma unroll
            for (int i = 0; i < 6; ++i) { const uint32_t t = P[i]; P[i] = t ^ cc; cc = t & cc; }
        }
    }

    // ---- fired = (2P >= A + thr), 7-bit bit-sliced compare ----
    uint32_t Y[7];
    {
        uint32_t c = 0;
#pragma unroll
        for (int i = 0; i < 7; ++i) {
            const uint32_t ai = (i < 6) ? A[i] : 0u;
            const uint32_t bm = ((thr >> i) & 1) ? 0xFFFFFFFFu : 0u;
            const uint32_t t  = ai ^ bm;
            Y[i] = t ^ c;
            c = (ai & bm) | (t & c);
        }
    }
    uint32_t bw = 0;
#pragma unroll
    for (int i = 0; i < 7; ++i) {
        const uint32_t xx = (i >= 1) ? P[i - 1] : 0u;
        const uint32_t d  = xx ^ Y[i];
        bw = ((~xx) & Y[i]) | ((~d) & bw);
    }
    const uint32_t fired = ~bw;

    // ---- OR across the 4 segment-waves ----
    fbuf[sw * 64 + lane] = fired;
    __syncthreads();
    if (sw == 0) {
        const uint32_t f = fbuf[lane] | fbuf[64 + lane] |
                           fbuf[128 + lane] | fbuf[192 + lane];
        outP[(size_t)w * H + h] = f;             // coalesced 4B stores
    }
}

// ---------------------------------------------------------------------------
// out[b][c] = sum_l sum_h act[l][b][h] * wout[l][h][c], act in {0,1}.
// Wave = one b; lanes = c. Grid = 32 b-groups x 32 h-chunks = 1024 blocks
// (4 blocks/CU, 16 waves/CU) [R9-proven]. 2-deep batched set-bit walk keeps
// two independent wout-row loads in flight.
// ---------------------------------------------------------------------------
#define NHC 32
#define HCH (H / NHC)   // 256 h per chunk

__global__ void final_kernel(const uint32_t* __restrict__ actP,
                             const float* __restrict__ wout,
                             float* __restrict__ out) {
    const int lane = threadIdx.x & 63;
    const int wid  = threadIdx.x >> 6;          // 0..3
    const int hc   = blockIdx.x & (NHC - 1);
    const int bg   = blockIdx.x / NHC;          // 0..31
    const int b    = bg * 4 + wid;              // wave-uniform
    const int w32  = b >> 5;                    // uniform within wave
    const int bit  = b & 31;

    float acc0 = 0.0f, acc1 = 0.0f;
    const int c1 = 64 + lane;
    const bool c1v = (c1 < C);

    for (int l = 0; l < L; ++l) {
        const uint32_t* aT = actP + ((size_t)l * 4 + w32) * H;
        const float* wl = wout + (size_t)l * H * C;
        for (int r = 0; r < HCH / 64; ++r) {
            const int hbase = hc * HCH + r * 64;
            const uint32_t m = aT[hbase + lane];
            uint64_t hm = __ballot((m >> bit) & 1u);
            while (hm) {
                const int s0 = __ffsll((unsigned long long)hm) - 1;
                hm &= hm - 1;
                const float* wr0 = wl + (size_t)(hbase + s0) * C;
                if (hm) {
                    const int s1 = __ffsll((unsigned long long)hm) - 1;
                    hm &= hm - 1;
                    const float* wr1 = wl + (size_t)(hbase + s1) * C;
                    const float a0 = wr0[lane];
                    const float a1 = wr1[lane];
                    const float b0 = c1v ? wr0[c1] : 0.0f;
                    const float b1 = c1v ? wr1[c1] : 0.0f;
                    acc0 += a0 + a1;
                    acc1 += b0 + b1;
                } else {
                    acc0 += wr0[lane];
                    if (c1v) acc1 += wr0[c1];
                }
            }
        }
    }
    atomicAdd(&out[b * C + lane], acc0);
    if (c1v) atomicAdd(&out[b * C + c1], acc1);
}

// ---------------------------------------------------------------------------
extern "C" void kernel_launch(void* const* d_in, const int* in_sizes, int n_in,
                              void* d_out, int out_size, void* d_ws, size_t ws_size,
                              hipStream_t stream) {
    const float* x      = (const float*)d_in[0];   // (B,F)
    const float* signs0 = (const float*)d_in[1];   // (S,H,K)
    const float* signsH = (const float*)d_in[2];   // (L-1,S,H,K)
    const float* wout   = (const float*)d_in[3];   // (L,H,C)
    const int*   idx0   = (const int*)d_in[4];     // (S,H,K)
    const int*   idxH   = (const int*)d_in[5];     // (L-1,S,H,K)
    const int*   thr    = (const int*)d_in[6];     // scalar
    float* out = (float*)d_out;                    // (B,C)

    // Workspace (planar u32): xP [4][F] (128 KiB), actP [L][4][H] (384 KiB)
    uint32_t* xP   = (uint32_t*)d_ws;
    uint32_t* actP = xP + (size_t)4 * F;

    // pack x + zero out (fused)
    pack_x_kernel<<<1024, 128, 0, stream>>>(x, xP, out);

    // layers: grid = 128 h-groups x 4 words = 512 blocks, 4 segment-waves each
    layer_kernel<<<512, 256, 0, stream>>>(xP, idx0, signs0, actP, thr);
    layer_kernel<<<512, 256, 0, stream>>>(actP, idxH, signsH,
                                          actP + (size_t)4 * H, thr);
    layer_kernel<<<512, 256, 0, stream>>>(actP + (size_t)4 * H,
                                          idxH + (size_t)S * H * K,
                                          signsH + (size_t)S * H * K,
                                          actP + (size_t)8 * H, thr);

    final_kernel<<<32 * NHC, 256, 0, stream>>>(actP, wout, out);
}